// Round 9
// baseline (10902.898 us; speedup 1.0000x reference)
//
#include <hip/hip_runtime.h>
#include <math.h>

#define B_ 8192
#define T_ 64
#define H_ 50
#define L_ 20
#define C_ 128
#define G3 150
#define JP 152          // padded row count in W tables (rows 0..149 used)
#define KQ 13           // k-quads (H padded to 52)
#define BB 32           // batch elements per block
#define NT 512          // threads per block

// ws layout (float offsets)
#define WS_GIF 0
#define WS_GID (WS_GIF + 128*JP)
#define WS_BL  (WS_GID + 128*JP)
#define WS_WOT (WS_BL + 128*52)

// LDS (floats): W0/W1/W2 [KQ][JP]f4, WO [KQ][128]f4, h1/h2 dbuf 2x[KQ][BB]f4,
// zbuf [BB][L], samp [BB]  -> 37,696 floats = 150,784 B (< 163,840)
#define SMEM_FLOATS (3*KQ*JP*4 + KQ*128*4 + 2*(2*KQ*BB*4) + BB*L_ + BB)
#define SMEM_BYTES  (SMEM_FLOATS*4)

__device__ __forceinline__ float dot4(float4 a, float4 b) {
  return ((a.x*b.x + a.y*b.y) + a.z*b.z) + a.w*b.w;
}
__device__ __forceinline__ float sigf(float v) { return 1.0f/(1.0f + expf(-v)); }

// ---------------------------------------------------------------------------
// Token tables: giF (enc input gates, r/z rows prefolded with bhh_f),
// giD (dec gru1 input gates from silu(embed_dec), r/z prefolded with bhh1),
// bL (backward-GRU output at h0=0), WOT (transposed k-quad Wh2o[:, :50]).
// ---------------------------------------------------------------------------
__global__ void tables_kernel(const float* __restrict__ embed_enc, const float* __restrict__ Wih_f,
                              const float* __restrict__ bih_f, const float* __restrict__ bhh_f,
                              const float* __restrict__ Wih_b, const float* __restrict__ bih_b,
                              const float* __restrict__ bhh_b,
                              const float* __restrict__ embed_dec, const float* __restrict__ Wih1,
                              const float* __restrict__ bih1, const float* __restrict__ bhh1,
                              const float* __restrict__ Wh2o, float* __restrict__ ws) {
  int tok = blockIdx.x;     // 0..127
  int tid = threadIdx.x;

  if (tid < JP) {
    int j = tid;
    float vF = 0.f, vD = 0.f;
    if (j < G3) {
      vF = bih_f[j];
      vD = bih1[j];
      for (int k = 0; k < H_; ++k) {
        float ee = embed_enc[tok*H_ + k];
        vF += ee * Wih_f[j*H_ + k];
        float ed = embed_dec[tok*H_ + k];
        float se = ed / (1.f + expf(-ed));   // silu
        vD += se * Wih1[j*70 + k];
      }
      if (j < 100) { vF += bhh_f[j]; vD += bhh1[j]; }
    }
    ws[WS_GIF + tok*JP + j] = vF;
    ws[WS_GID + tok*JP + j] = vD;
  }

  if (tid < 52) {
    int u = tid;
    float v = 0.f;
    if (u < H_) {
      float gr = bih_b[u], gzv = bih_b[50+u], gn = bih_b[100+u];
      for (int k = 0; k < H_; ++k) {
        float ee = embed_enc[tok*H_ + k];
        gr  += ee * Wih_b[u*H_ + k];
        gzv += ee * Wih_b[(50+u)*H_ + k];
        gn  += ee * Wih_b[(100+u)*H_ + k];
      }
      float r  = sigf(gr + bhh_b[u]);
      float zg = sigf(gzv + bhh_b[50+u]);
      float n  = tanhf(gn + r*bhh_b[100+u]);
      v = (1.f - zg)*n;
    }
    ws[WS_BL + tok*52 + u] = v;
  }

  if (tok == 0) {
    for (int i = tid; i < KQ*128*4; i += blockDim.x) {
      int l  = i & 3;
      int c  = (i >> 2) & 127;
      int kq = i >> 9;
      int k  = kq*4 + l;
      ws[WS_WOT + i] = (k < H_) ? Wh2o[c*70 + k] : 0.f;
    }
  }
}

// ---------------------------------------------------------------------------
// Fused kernel. Thread (s,e) owns gate rows {u, 50+u, 100+u} for u=s (and
// u=s+32 when s<18) x 2 elems -> gates computed entirely in registers.
// h1/h2 double-buffered in LDS (1 barrier/enc step, 3/dec step). No gbuf.
// ---------------------------------------------------------------------------
__global__ __launch_bounds__(NT, 1)
void vae_kernel(const int* __restrict__ x,
                const float* __restrict__ Whh_f, const float* __restrict__ bhh_f,
                const float* __restrict__ Wh2p,  const float* __restrict__ bh2p,
                const float* __restrict__ Wz2h,  const float* __restrict__ bz2h,
                const float* __restrict__ Wih1,  const float* __restrict__ bhh1,
                const float* __restrict__ Whh1,
                const float* __restrict__ Wih2,  const float* __restrict__ bih2,
                const float* __restrict__ bhh2,  const float* __restrict__ Whh2,
                const float* __restrict__ Wh2o,  const float* __restrict__ bh2o,
                const float* __restrict__ ws, float* __restrict__ out) {
  extern __shared__ __align__(16) float smem[];
  float4* W0  = (float4*)smem;            // [KQ][JP]
  float4* W1  = W0 + KQ*JP;
  float4* W2  = W1 + KQ*JP;
  float4* WO  = W2 + KQ*JP;               // [KQ][128]
  float4* h1q = WO + KQ*128;              // 2 x [KQ][BB]
  float4* h2q = h1q + 2*KQ*BB;            // 2 x [KQ][BB]
  float*  zbuf = (float*)(h2q + 2*KQ*BB); // [BB][L]
  int*    samp = (int*)(zbuf + BB*L_);    // [BB]

  const int tid = threadIdx.x;
  const int s   = tid & 31;
  const int gg  = tid >> 5;               // 0..15
  const int e0  = gg, e1 = gg + 16;
  const int blk = blockIdx.x;
  const int elem0 = blk*BB + e0, elem1 = blk*BB + e1;
  const bool has2 = (s < 18);
  const int u1 = s, u2 = s + 32;          // u2 valid iff has2

  const float* giF = ws + WS_GIF;
  const float* giD = ws + WS_GID;
  const float* bL  = ws + WS_BL;
  const float4* WOT = (const float4*)(ws + WS_WOT);

  // ---- stage encoder weights (W0 <- Whh_f), zero both h buffers ----
  for (int i = tid; i < KQ*JP; i += NT) {
    int kq = i / JP, j = i - kq*JP;
    float4 v = {0.f,0.f,0.f,0.f};
    if (j < G3) {
      int k0 = kq*4;
      v.x = Whh_f[j*H_ + k0];
      if (k0+1 < H_) v.y = Whh_f[j*H_ + k0+1];
      if (k0+2 < H_) v.z = Whh_f[j*H_ + k0+2];
      if (k0+3 < H_) v.w = Whh_f[j*H_ + k0+3];
    }
    W0[i] = v;
  }
  for (int i = tid; i < 2*KQ*BB; i += NT) {
    float4 zz = {0.f,0.f,0.f,0.f};
    h1q[i] = zz; h2q[i] = zz;
  }
  __syncthreads();

  // encoder n-row biases (registers)
  const float bfn1 = bhh_f[100 + u1];
  const float bfn2 = has2 ? bhh_f[100 + u2] : 0.f;

  int cur = 0;
  // =================== ENCODER (64 steps, 1 barrier each) ===================
  for (int t = 0; t < T_; ++t) {
    const int tok0 = x[elem0*T_ + t];
    const int tok1 = x[elem1*T_ + t];
    const float4* hc = h1q + cur*KQ*BB;

    float ar[2], az[2], an[2], ar2[2], az2[2], an2[2];
    ar[0] = giF[tok0*JP + u1];      ar[1] = giF[tok1*JP + u1];
    az[0] = giF[tok0*JP + 50 + u1]; az[1] = giF[tok1*JP + 50 + u1];
    an[0] = bfn1;                   an[1] = bfn1;
    if (has2) {
      ar2[0] = giF[tok0*JP + u2];      ar2[1] = giF[tok1*JP + u2];
      az2[0] = giF[tok0*JP + 50 + u2]; az2[1] = giF[tok1*JP + 50 + u2];
      an2[0] = bfn2;                   an2[1] = bfn2;
    }
#pragma unroll
    for (int kq = 0; kq < KQ; ++kq) {
      float4 ha = hc[kq*BB + e0];
      float4 hb = hc[kq*BB + e1];
      float4 wr = W0[kq*JP + u1];
      float4 wz = W0[kq*JP + 50 + u1];
      float4 wn = W0[kq*JP + 100 + u1];
      ar[0] += dot4(wr, ha); ar[1] += dot4(wr, hb);
      az[0] += dot4(wz, ha); az[1] += dot4(wz, hb);
      an[0] += dot4(wn, ha); an[1] += dot4(wn, hb);
      if (has2) {
        float4 wr2 = W0[kq*JP + u2];
        float4 wz2 = W0[kq*JP + 50 + u2];
        float4 wn2 = W0[kq*JP + 100 + u2];
        ar2[0] += dot4(wr2, ha); ar2[1] += dot4(wr2, hb);
        az2[0] += dot4(wz2, ha); az2[1] += dot4(wz2, hb);
        an2[0] += dot4(wn2, ha); an2[1] += dot4(wn2, hb);
      }
    }
    // gates in registers -> h_new into the other buffer
    float* hn = (float*)(h1q + (cur^1)*KQ*BB);
    const float* ho = (const float*)hc;
#pragma unroll
    for (int ei = 0; ei < 2; ++ei) {
      int e = (ei == 0) ? e0 : e1;
      int tok = (ei == 0) ? tok0 : tok1;
      {
        float r = sigf(ar[ei]), zg = sigf(az[ei]);
        float inn = giF[tok*JP + 100 + u1];
        float n = tanhf(inn + r*an[ei]);
        int off = (u1>>2)*(BB*4) + e*4 + (u1&3);
        float hv = (1.f - zg)*n + zg*ho[off];
        if (t == T_-1) hv += bL[tok*52 + u1];
        hn[off] = hv;
      }
      if (has2) {
        float r = sigf(ar2[ei]), zg = sigf(az2[ei]);
        float inn = giF[tok*JP + 100 + u2];
        float n = tanhf(inn + r*an2[ei]);
        int off = (u2>>2)*(BB*4) + e*4 + (u2&3);
        float hv = (1.f - zg)*n + zg*ho[off];
        if (t == T_-1) hv += bL[tok*52 + u2];
        hn[off] = hv;
      }
    }
    __syncthreads();
    cur ^= 1;
  }
  // h_enc (incl. b_last) now in h1q buffer 0  (cur == 0)

  // =================== PROJECTION / LATENT ===================
  const long WORDS = (long)B_*T_*C_;
  const long MUOFF = WORDS;
  const long LVOFF = WORDS + (long)B_*L_;
  const float* henc = (const float*)h1q;        // buffer 0, flat
  for (int i = tid; i < BB*2*L_; i += NT) {
    int e = i & 31, c = i >> 5;                 // c 0..39
    float a = bh2p[c];
    for (int k = 0; k < H_; ++k)
      a += henc[(k>>2)*(BB*4) + e*4 + (k&3)] * Wh2p[c*H_ + k];
    int elem = blk*BB + e;
    if (c < L_) { out[MUOFF + (long)elem*L_ + c] = a; zbuf[e*L_ + c] = a; }
    else        { out[LVOFF + (long)elem*L_ + (c - L_)] = a; }
  }
  __syncthreads();

  // h_init -> h1[0], h2[0]
  for (int i = tid; i < BB*H_; i += NT) {
    int e = i & 31, u = i >> 5;
    float a = bz2h[u];
    for (int k = 0; k < L_; ++k) a += zbuf[e*L_ + k] * Wz2h[u*L_ + k];
    int off = (u>>2)*(BB*4) + e*4 + (u&3);
    ((float*)h1q)[off] = a;
    ((float*)h2q)[off] = a;
  }

  // restage decoder weights: W0<-Whh1, W1<-Wih2, W2<-Whh2, WO<-WOT
  for (int i = tid; i < KQ*JP; i += NT) {
    int kq = i / JP, j = i - kq*JP;
    float4 v1 = {0.f,0.f,0.f,0.f}, v2 = v1, v3 = v1;
    if (j < G3) {
      int k0 = kq*4;
      v1.x = Whh1[j*H_+k0];  v2.x = Wih2[j*H_+k0];  v3.x = Whh2[j*H_+k0];
      if (k0+1 < H_) { v1.y = Whh1[j*H_+k0+1]; v2.y = Wih2[j*H_+k0+1]; v3.y = Whh2[j*H_+k0+1]; }
      if (k0+2 < H_) { v1.z = Whh1[j*H_+k0+2]; v2.z = Wih2[j*H_+k0+2]; v3.z = Whh2[j*H_+k0+2]; }
      if (k0+3 < H_) { v1.w = Whh1[j*H_+k0+3]; v2.w = Wih2[j*H_+k0+3]; v3.w = Whh2[j*H_+k0+3]; }
    }
    W0[i] = v1; W1[i] = v2; W2[i] = v3;
  }
  for (int i = tid; i < KQ*128; i += NT) WO[i] = WOT[i];
  if (tid < BB) samp[tid] = 1;   // SOS

  // per-thread z-derived constants (read zbuf; no writer until next barrier)
  float gzr[2][2], gzz[2][2], gzn[2][2];   // [u-slot][elem]
#pragma unroll
  for (int us = 0; us < 2; ++us) {
    int u = (us == 0) ? u1 : u2;
    float r0=0.f, r1=0.f, z0=0.f, z1=0.f, n0=0.f, n1=0.f;
    if (us == 0 || has2) {
      for (int k = 0; k < L_; ++k) {
        float wr = Wih1[u*70 + 50 + k];
        float wz = Wih1[(50+u)*70 + 50 + k];
        float wn = Wih1[(100+u)*70 + 50 + k];
        float za = zbuf[e0*L_ + k], zb = zbuf[e1*L_ + k];
        r0 += za*wr; r1 += zb*wr;
        z0 += za*wz; z1 += zb*wz;
        n0 += za*wn; n1 += zb*wn;
      }
    }
    gzr[us][0]=r0; gzr[us][1]=r1; gzz[us][0]=z0; gzz[us][1]=z1; gzn[us][0]=n0; gzn[us][1]=n1;
  }
  float ozr[4][2];
#pragma unroll
  for (int q = 0; q < 4; ++q) {
    int c = s + 32*q;
    float a0 = bh2o[c], a1 = bh2o[c];
    for (int k = 0; k < L_; ++k) {
      float wck = Wh2o[c*70 + 50 + k];
      a0 += zbuf[e0*L_ + k]*wck;
      a1 += zbuf[e1*L_ + k]*wck;
    }
    ozr[q][0] = a0; ozr[q][1] = a1;
  }

  // decoder bias registers
  const float b1n1 = bhh1[100 + u1];
  const float b1n2 = has2 ? bhh1[100 + u2] : 0.f;
  const float b2r1 = bih2[u1] + bhh2[u1];
  const float b2z1 = bih2[50+u1] + bhh2[50+u1];
  const float b2i1 = bih2[100+u1];
  const float b2h1 = bhh2[100+u1];
  const float b2r2 = has2 ? (bih2[u2] + bhh2[u2]) : 0.f;
  const float b2z2 = has2 ? (bih2[50+u2] + bhh2[50+u2]) : 0.f;
  const float b2i2 = has2 ? bih2[100+u2] : 0.f;
  const float b2h2 = has2 ? bhh2[100+u2] : 0.f;

  __syncthreads();
  cur = 0;

  // =================== DECODER (64 steps, 3 barriers each) ===================
  for (int t = 0; t < T_; ++t) {
    const int c0 = samp[e0], c1 = samp[e1];
    const float4* h1c = h1q + cur*KQ*BB;
    const float4* h2c = h2q + cur*KQ*BB;
    float4* h1n4 = h1q + (cur^1)*KQ*BB;
    float4* h2n4 = h2q + (cur^1)*KQ*BB;

    // ---- g1: gi(table)+gz + h1@Whh1.T ----
    float ar[2], az[2], an[2], ar2[2], az2[2], an2[2];
    ar[0] = giD[c0*JP + u1] + gzr[0][0];      ar[1] = giD[c1*JP + u1] + gzr[0][1];
    az[0] = giD[c0*JP + 50 + u1] + gzz[0][0]; az[1] = giD[c1*JP + 50 + u1] + gzz[0][1];
    an[0] = b1n1;                             an[1] = b1n1;
    if (has2) {
      ar2[0] = giD[c0*JP + u2] + gzr[1][0];      ar2[1] = giD[c1*JP + u2] + gzr[1][1];
      az2[0] = giD[c0*JP + 50 + u2] + gzz[1][0]; az2[1] = giD[c1*JP + 50 + u2] + gzz[1][1];
      an2[0] = b1n2;                             an2[1] = b1n2;
    }
#pragma unroll
    for (int kq = 0; kq < KQ; ++kq) {
      float4 ha = h1c[kq*BB + e0];
      float4 hb = h1c[kq*BB + e1];
      float4 wr = W0[kq*JP + u1];
      float4 wz = W0[kq*JP + 50 + u1];
      float4 wn = W0[kq*JP + 100 + u1];
      ar[0] += dot4(wr, ha); ar[1] += dot4(wr, hb);
      az[0] += dot4(wz, ha); az[1] += dot4(wz, hb);
      an[0] += dot4(wn, ha); an[1] += dot4(wn, hb);
      if (has2) {
        float4 wr2 = W0[kq*JP + u2];
        float4 wz2 = W0[kq*JP + 50 + u2];
        float4 wn2 = W0[kq*JP + 100 + u2];
        ar2[0] += dot4(wr2, ha); ar2[1] += dot4(wr2, hb);
        az2[0] += dot4(wz2, ha); az2[1] += dot4(wz2, hb);
        an2[0] += dot4(wn2, ha); an2[1] += dot4(wn2, hb);
      }
    }
    {
      const float* ho = (const float*)h1c;
      float* hn = (float*)h1n4;
#pragma unroll
      for (int ei = 0; ei < 2; ++ei) {
        int e = (ei == 0) ? e0 : e1;
        int c = (ei == 0) ? c0 : c1;
        {
          float r = sigf(ar[ei]), zg = sigf(az[ei]);
          float inn = giD[c*JP + 100 + u1] + gzn[0][ei];
          float n = tanhf(inn + r*an[ei]);
          int off = (u1>>2)*(BB*4) + e*4 + (u1&3);
          hn[off] = (1.f - zg)*n + zg*ho[off];
        }
        if (has2) {
          float r = sigf(ar2[ei]), zg = sigf(az2[ei]);
          float inn = giD[c*JP + 100 + u2] + gzn[1][ei];
          float n = tanhf(inn + r*an2[ei]);
          int off = (u2>>2)*(BB*4) + e*4 + (u2&3);
          hn[off] = (1.f - zg)*n + zg*ho[off];
        }
      }
    }
    __syncthreads();

    // ---- g2: (h1new@Wih2.T) + (h2@Whh2.T); n-gate i/h parts separate ----
    float br[2], bz[2], bni[2], bnh[2], br2[2], bz2[2], bni2[2], bnh2[2];
    br[0] = b2r1; br[1] = b2r1;   bz[0] = b2z1; bz[1] = b2z1;
    bni[0] = b2i1; bni[1] = b2i1; bnh[0] = b2h1; bnh[1] = b2h1;
    if (has2) {
      br2[0] = b2r2; br2[1] = b2r2;   bz2[0] = b2z2; bz2[1] = b2z2;
      bni2[0] = b2i2; bni2[1] = b2i2; bnh2[0] = b2h2; bnh2[1] = b2h2;
    }
#pragma unroll
    for (int kq = 0; kq < KQ; ++kq) {
      float4 p1a = h1n4[kq*BB + e0], p1b = h1n4[kq*BB + e1];
      float4 p2a = h2c[kq*BB + e0],  p2b = h2c[kq*BB + e1];
      float4 ir = W1[kq*JP + u1], hr = W2[kq*JP + u1];
      float4 iz = W1[kq*JP + 50 + u1], hz = W2[kq*JP + 50 + u1];
      float4 in_ = W1[kq*JP + 100 + u1], hn_ = W2[kq*JP + 100 + u1];
      br[0]  += dot4(ir, p1a) + dot4(hr, p2a);  br[1]  += dot4(ir, p1b) + dot4(hr, p2b);
      bz[0]  += dot4(iz, p1a) + dot4(hz, p2a);  bz[1]  += dot4(iz, p1b) + dot4(hz, p2b);
      bni[0] += dot4(in_, p1a);                 bni[1] += dot4(in_, p1b);
      bnh[0] += dot4(hn_, p2a);                 bnh[1] += dot4(hn_, p2b);
      if (has2) {
        float4 ir2 = W1[kq*JP + u2], hr2 = W2[kq*JP + u2];
        float4 iz2 = W1[kq*JP + 50 + u2], hz2 = W2[kq*JP + 50 + u2];
        float4 in2 = W1[kq*JP + 100 + u2], hn2 = W2[kq*JP + 100 + u2];
        br2[0]  += dot4(ir2, p1a) + dot4(hr2, p2a);  br2[1]  += dot4(ir2, p1b) + dot4(hr2, p2b);
        bz2[0]  += dot4(iz2, p1a) + dot4(hz2, p2a);  bz2[1]  += dot4(iz2, p1b) + dot4(hz2, p2b);
        bni2[0] += dot4(in2, p1a);                   bni2[1] += dot4(in2, p1b);
        bnh2[0] += dot4(hn2, p2a);                   bnh2[1] += dot4(hn2, p2b);
      }
    }
    {
      const float* ho = (const float*)h2c;
      float* hn = (float*)h2n4;
#pragma unroll
      for (int ei = 0; ei < 2; ++ei) {
        int e = (ei == 0) ? e0 : e1;
        {
          float r = sigf(br[ei]), zg = sigf(bz[ei]);
          float n = tanhf(bni[ei] + r*bnh[ei]);
          int off = (u1>>2)*(BB*4) + e*4 + (u1&3);
          hn[off] = (1.f - zg)*n + zg*ho[off];
        }
        if (has2) {
          float r = sigf(br2[ei]), zg = sigf(bz2[ei]);
          float n = tanhf(bni2[ei] + r*bnh2[ei]);
          int off = (u2>>2)*(BB*4) + e*4 + (u2&3);
          hn[off] = (1.f - zg)*n + zg*ho[off];
        }
      }
    }
    __syncthreads();

    // ---- o = [h2new,z]@Wh2o.T + bh2o ; log_softmax ; argmax ; store ----
    float o[4][2];
#pragma unroll
    for (int q = 0; q < 4; ++q) { o[q][0] = ozr[q][0]; o[q][1] = ozr[q][1]; }
#pragma unroll
    for (int kq = 0; kq < KQ; ++kq) {
      float4 ha = h2n4[kq*BB + e0];
      float4 hb = h2n4[kq*BB + e1];
#pragma unroll
      for (int q = 0; q < 4; ++q) {
        float4 w = WO[kq*128 + s + 32*q];
        o[q][0] += dot4(w, ha);
        o[q][1] += dot4(w, hb);
      }
    }
#pragma unroll
    for (int ei = 0; ei < 2; ++ei) {
      float bv = o[0][ei]; int bi = s;
#pragma unroll
      for (int q = 1; q < 4; ++q) {
        int c = s + 32*q;
        if (o[q][ei] > bv) { bv = o[q][ei]; bi = c; }
      }
#pragma unroll
      for (int mask = 16; mask >= 1; mask >>= 1) {
        float ov = __shfl_xor(bv, mask);
        int   oi = __shfl_xor(bi, mask);
        if (ov > bv || (ov == bv && oi < bi)) { bv = ov; bi = oi; }
      }
      float ssum = 0.f;
#pragma unroll
      for (int q = 0; q < 4; ++q) ssum += expf(o[q][ei] - bv);
#pragma unroll
      for (int mask = 16; mask >= 1; mask >>= 1) ssum += __shfl_xor(ssum, mask);
      float lg = logf(ssum);
      int elem = (ei == 0) ? elem0 : elem1;
      long base = (long)elem*T_*C_ + (long)t*C_;
#pragma unroll
      for (int q = 0; q < 4; ++q)
        __builtin_nontemporal_store(o[q][ei] - bv - lg, &out[base + s + 32*q]);
      if (s == 0) samp[(ei == 0) ? e0 : e1] = bi;
    }
    __syncthreads();
    cur ^= 1;
  }
}

// ---------------------------------------------------------------------------
extern "C" void kernel_launch(void* const* d_in, const int* in_sizes, int n_in,
                              void* d_out, int out_size, void* d_ws, size_t ws_size,
                              hipStream_t stream) {
  const int*   x         = (const int*)  d_in[0];
  const float* embed_enc = (const float*)d_in[1];
  const float* Wih_f     = (const float*)d_in[2];
  const float* Whh_f     = (const float*)d_in[3];
  const float* bih_f     = (const float*)d_in[4];
  const float* bhh_f     = (const float*)d_in[5];
  const float* Wih_b     = (const float*)d_in[6];
  const float* bih_b     = (const float*)d_in[8];
  const float* bhh_b     = (const float*)d_in[9];
  const float* Wh2p      = (const float*)d_in[10];
  const float* bh2p      = (const float*)d_in[11];
  const float* embed_dec = (const float*)d_in[12];
  const float* Wz2h      = (const float*)d_in[13];
  const float* bz2h      = (const float*)d_in[14];
  const float* Wih1      = (const float*)d_in[15];
  const float* Whh1      = (const float*)d_in[16];
  const float* bih1      = (const float*)d_in[17];
  const float* bhh1      = (const float*)d_in[18];
  const float* Wih2      = (const float*)d_in[19];
  const float* Whh2      = (const float*)d_in[20];
  const float* bih2      = (const float*)d_in[21];
  const float* bhh2      = (const float*)d_in[22];
  const float* Wh2o      = (const float*)d_in[23];
  const float* bh2o      = (const float*)d_in[24];
  float* out = (float*)d_out;
  float* ws  = (float*)d_ws;

  hipFuncSetAttribute((const void*)vae_kernel,
                      hipFuncAttributeMaxDynamicSharedMemorySize, SMEM_BYTES);

  tables_kernel<<<128, 256, 0, stream>>>(embed_enc, Wih_f, bih_f, bhh_f,
                                         Wih_b, bih_b, bhh_b,
                                         embed_dec, Wih1, bih1, bhh1, Wh2o, ws);

  vae_kernel<<<B_/BB, NT, SMEM_BYTES, stream>>>(x, Whh_f, bhh_f, Wh2p, bh2p,
                                                Wz2h, bz2h, Wih1, bhh1, Whh1,
                                                Wih2, bih2, bhh2, Whh2,
                                                Wh2o, bh2o, ws, out);
}

// Round 12
// 3459.410 us; speedup vs baseline: 3.1517x; 3.1517x over previous
//
#include <hip/hip_runtime.h>
#include <math.h>

#define B_ 8192
#define T_ 64
#define H_ 50
#define L_ 20
#define C_ 128
#define G3 150
#define JP 152          // padded gate-row count in LDS slots / tables
#define KQ 13           // k-quads (H padded to 52)
#define BB 32           // batch elements per block
#define NT 512          // threads per block

// ws layout (float offsets)
#define WS_GIF 0
#define WS_GID (WS_GIF + 128*JP)
#define WS_BL  (WS_GID + 128*JP)
#define WS_WOT (WS_BL + 128*52)

// LDS: W0/W1/W2 [KQ][JP] f4, WO [KQ][128] f4, hq1/hq2 [KQ][BB] f4,
// gbuf [BB][151], gzn [BB][52], bias2n[52], samp[BB], tokb[BB]
// total = 161,232 B <= 163,840 B
#define SMEM_FLOATS (3*KQ*JP*4 + KQ*128*4 + 2*KQ*BB*4 + BB*151 + BB*52 + 52 + BB + BB)
#define SMEM_BYTES  (SMEM_FLOATS*4)

__device__ __forceinline__ float dot4(float4 a, float4 b) {
  return ((a.x*b.x + a.y*b.y) + a.z*b.z) + a.w*b.w;
}
__device__ __forceinline__ float sigf(float v) { return 1.0f/(1.0f + expf(-v)); }

// ---------------------------------------------------------------------------
// Precompute token tables (unchanged).
// ---------------------------------------------------------------------------
__global__ void tables_kernel(const float* __restrict__ embed_enc, const float* __restrict__ Wih_f,
                              const float* __restrict__ bih_f, const float* __restrict__ bhh_f,
                              const float* __restrict__ Wih_b, const float* __restrict__ bih_b,
                              const float* __restrict__ bhh_b,
                              const float* __restrict__ embed_dec, const float* __restrict__ Wih1,
                              const float* __restrict__ bih1, const float* __restrict__ bhh1,
                              const float* __restrict__ Wh2o, float* __restrict__ ws) {
  int tok = blockIdx.x;     // 0..127
  int tid = threadIdx.x;

  if (tid < JP) {
    int j = tid;
    float vF = 0.f, vD = 0.f;
    if (j < G3) {
      vF = bih_f[j];
      vD = bih1[j];
      for (int k = 0; k < H_; ++k) {
        float ee = embed_enc[tok*H_ + k];
        vF += ee * Wih_f[j*H_ + k];
        float ed = embed_dec[tok*H_ + k];
        float se = ed / (1.f + expf(-ed));   // silu
        vD += se * Wih1[j*70 + k];
      }
      if (j < 100) { vF += bhh_f[j]; vD += bhh1[j]; }  // fold bhh into r/z rows
    }
    ws[WS_GIF + tok*JP + j] = vF;
    ws[WS_GID + tok*JP + j] = vD;
  }

  if (tid < 52) {
    int u = tid;
    float v = 0.f;
    if (u < H_) {
      float gr = bih_b[u], gzv = bih_b[50+u], gn = bih_b[100+u];
      for (int k = 0; k < H_; ++k) {
        float ee = embed_enc[tok*H_ + k];
        gr  += ee * Wih_b[u*H_ + k];
        gzv += ee * Wih_b[(50+u)*H_ + k];
        gn  += ee * Wih_b[(100+u)*H_ + k];
      }
      float r  = sigf(gr + bhh_b[u]);
      float zg = sigf(gzv + bhh_b[50+u]);
      float n  = tanhf(gn + r*bhh_b[100+u]);
      v = (1.f - zg)*n;
    }
    ws[WS_BL + tok*52 + u] = v;
  }

  if (tok == 0) {
    for (int i = tid; i < KQ*128*4; i += blockDim.x) {
      int l  = i & 3;
      int c  = (i >> 2) & 127;
      int kq = i >> 9;
      int k  = kq*4 + l;
      ws[WS_WOT + i] = (k < H_) ? Wh2o[c*70 + k] : 0.f;
    }
  }
}

// ---------------------------------------------------------------------------
// Main fused kernel (round-5 structure; gate passes u-major for coalesced
// table gathers).
// ---------------------------------------------------------------------------
__global__ __launch_bounds__(NT, 1)
void vae_kernel(const int* __restrict__ x,
                const float* __restrict__ Whh_f, const float* __restrict__ bhh_f,
                const float* __restrict__ Wh2p,  const float* __restrict__ bh2p,
                const float* __restrict__ Wz2h,  const float* __restrict__ bz2h,
                const float* __restrict__ Wih1,  const float* __restrict__ bhh1,
                const float* __restrict__ Whh1,
                const float* __restrict__ Wih2,  const float* __restrict__ bih2,
                const float* __restrict__ bhh2,  const float* __restrict__ Whh2,
                const float* __restrict__ Wh2o,  const float* __restrict__ bh2o,
                const float* __restrict__ ws, float* __restrict__ out) {
  extern __shared__ __align__(16) float smem[];
  float4* W0  = (float4*)smem;            // [KQ][JP]
  float4* W1  = W0 + KQ*JP;
  float4* W2  = W1 + KQ*JP;
  float4* WO  = W2 + KQ*JP;               // [KQ][128]
  float4* hq1 = WO + KQ*128;              // [KQ][BB]
  float4* hq2 = hq1 + KQ*BB;
  float*  gbuf = (float*)(hq2 + KQ*BB);   // [BB][151]
  float*  gzn  = gbuf + BB*151;           // [BB][52]
  float*  bias2n = gzn + BB*52;           // [52]
  int*    samp = (int*)(bias2n + 52);     // [BB]
  int*    tokb = samp + BB;               // [BB]
  float*  zl   = gbuf;                    // alias during latent phase

  const int tid = threadIdx.x;
  const int s   = tid & 31;
  const int gg  = tid >> 5;               // 0..15
  const int e0  = gg, e1 = gg + 16;
  const int blk = blockIdx.x;
  const int elem0 = blk*BB + e0, elem1 = blk*BB + e1;

  const float* giF = ws + WS_GIF;
  const float* giD = ws + WS_GID;
  const float* bL  = ws + WS_BL;
  const float4* WOT = (const float4*)(ws + WS_WOT);

  const int jq4 = (s < 22) ? (s + 128) : 150;   // q=4 row (150/151 are zero rows)

  // ---- stage encoder weights, zero h ----
  for (int i = tid; i < KQ*JP; i += NT) {
    int kq = i / JP, j = i - kq*JP;
    float4 v = {0.f,0.f,0.f,0.f};
    if (j < G3) {
      int k0 = kq*4;
      v.x = Whh_f[j*H_ + k0];
      if (k0+1 < H_) v.y = Whh_f[j*H_ + k0+1];
      if (k0+2 < H_) v.z = Whh_f[j*H_ + k0+2];
      if (k0+3 < H_) v.w = Whh_f[j*H_ + k0+3];
    }
    W0[i] = v;
  }
  for (int i = tid; i < KQ*BB; i += NT) {
    float4 zz = {0.f,0.f,0.f,0.f};
    hq1[i] = zz; hq2[i] = zz;
  }
  __syncthreads();

  // loop-invariant encoder biases -> registers
  const float bhfA = bhh_f[s + 96];                     // used when s>=4 (j=s+96>=100)
  const float bhfB = (s < 22) ? bhh_f[s + 128] : 0.f;

  // =================== ENCODER (64 steps) ===================
  for (int t = 0; t < T_; ++t) {
    int tok0 = x[elem0*T_ + t];
    int tok1 = x[elem1*T_ + t];
    if (s == 0) { tokb[e0] = tok0; tokb[e1] = tok1; }
    float acc[5][2];
#pragma unroll
    for (int q = 0; q < 3; ++q) {           // j = s+32q <= 95 < 100 always
      int j = s + 32*q;
      acc[q][0] = giF[tok0*JP + j]; acc[q][1] = giF[tok1*JP + j];
    }
    if (s < 4) { acc[3][0] = giF[tok0*JP + s + 96]; acc[3][1] = giF[tok1*JP + s + 96]; }
    else       { acc[3][0] = bhfA; acc[3][1] = bhfA; }
    acc[4][0] = bhfB; acc[4][1] = bhfB;
#pragma unroll
    for (int kq = 0; kq < KQ; ++kq) {
      float4 ha = hq1[kq*BB + e0];
      float4 hb = hq1[kq*BB + e1];
#pragma unroll
      for (int q = 0; q < 4; ++q) {
        float4 w = W0[kq*JP + s + 32*q];
        acc[q][0] += dot4(w, ha);
        acc[q][1] += dot4(w, hb);
      }
      { float4 w = W0[kq*JP + jq4];
        acc[4][0] += dot4(w, ha);
        acc[4][1] += dot4(w, hb); }
    }
#pragma unroll
    for (int q = 0; q < 4; ++q) {
      int j = s + 32*q;
      gbuf[e0*151 + j] = acc[q][0];
      gbuf[e1*151 + j] = acc[q][1];
    }
    if (s < 22) { int j = s+128; gbuf[e0*151+j] = acc[4][0]; gbuf[e1*151+j] = acc[4][1]; }
    __syncthreads();

    // gate pass: u-major -> giF reads coalesced (128B per 32-lane segment)
    for (int i = tid; i < BB*64; i += NT) {
      int u = i & 63, e = i >> 6;
      if (u < H_) {
        int tok = tokb[e];
        float r   = sigf(gbuf[e*151 + u]);
        float zg  = sigf(gbuf[e*151 + 50 + u]);
        float inn = giF[tok*JP + 100 + u];
        float n   = tanhf(inn + r*gbuf[e*151 + 100 + u]);
        float* hp = (float*)hq1 + (u>>2)*BB*4 + e*4 + (u&3);
        float ho = *hp;
        *hp = (1.f - zg)*n + zg*ho;
      }
    }
    __syncthreads();
  }

  // ---- h_enc = f_last + b_last(table), u-major coalesced ----
  for (int i = tid; i < BB*64; i += NT) {
    int u = i & 63, e = i >> 6;
    if (u < H_) {
      int tok = tokb[e];                    // t=63 tokens still staged
      float* hp = (float*)hq1 + (u>>2)*BB*4 + e*4 + (u&3);
      *hp += bL[tok*52 + u];
    }
  }
  __syncthreads();

  // =================== PROJECTION / LATENT ===================
  const long WORDS = (long)B_*T_*C_;
  const long MUOFF = WORDS;
  const long LVOFF = WORDS + (long)B_*L_;
  for (int i = tid; i < BB*2*L_; i += NT) {     // 1280 tasks
    int e = i & 31, c = i >> 5;                 // c 0..39
    float a = bh2p[c];
    for (int k = 0; k < H_; ++k)
      a += ((float*)hq1)[(k>>2)*BB*4 + e*4 + (k&3)] * Wh2p[c*H_ + k];
    int elem = blk*BB + e;
    if (c < L_) { out[MUOFF + (long)elem*L_ + c] = a; zl[e*L_ + c] = a; }
    else        { out[LVOFF + (long)elem*L_ + (c - L_)] = a; }
  }
  __syncthreads();

  // h_init -> h1, h2 ; gzn (n-part of z@Wih1[:,50:].T)
  for (int i = tid; i < BB*H_; i += NT) {
    int e = i & 31, u = i >> 5;
    float a = bz2h[u];
    for (int k = 0; k < L_; ++k) a += zl[e*L_ + k] * Wz2h[u*L_ + k];
    ((float*)hq1)[(u>>2)*BB*4 + e*4 + (u&3)] = a;
    ((float*)hq2)[(u>>2)*BB*4 + e*4 + (u&3)] = a;
    float gn = 0.f;
    for (int k = 0; k < L_; ++k) gn += zl[e*L_ + k] * Wih1[(100+u)*70 + 50 + k];
    gzn[e*52 + u] = gn;
  }

  // per-thread constants: gz (r/z rows of z-part for gru1), oz (z-part of output)
  float gz[5][2];
#pragma unroll
  for (int q = 0; q < 5; ++q) {
    int j = s + 32*q;
    float a0 = 0.f, a1 = 0.f;
    if (j < 100) {
      for (int k = 0; k < L_; ++k) {
        float wjk = Wih1[j*70 + 50 + k];
        a0 += zl[e0*L_ + k]*wjk;
        a1 += zl[e1*L_ + k]*wjk;
      }
    }
    gz[q][0] = a0; gz[q][1] = a1;
  }
  float ozr[4][2];
#pragma unroll
  for (int q = 0; q < 4; ++q) {
    int c = s + 32*q;
    float a0 = bh2o[c], a1 = bh2o[c];
    for (int k = 0; k < L_; ++k) {
      float wck = Wh2o[c*70 + 50 + k];
      a0 += zl[e0*L_ + k]*wck;
      a1 += zl[e1*L_ + k]*wck;
    }
    ozr[q][0] = a0; ozr[q][1] = a1;
  }
  __syncthreads();   // zl reads done

  // ---- restage decoder weights + WO tile + n-bias ----
  for (int i = tid; i < KQ*JP; i += NT) {
    int kq = i / JP, j = i - kq*JP;
    float4 v1 = {0.f,0.f,0.f,0.f}, v2 = v1, v3 = v1;
    if (j < G3) {
      int k0 = kq*4;
      v1.x = Whh1[j*H_+k0];  v2.x = Wih2[j*H_+k0];  v3.x = Whh2[j*H_+k0];
      if (k0+1 < H_) { v1.y = Whh1[j*H_+k0+1]; v2.y = Wih2[j*H_+k0+1]; v3.y = Whh2[j*H_+k0+1]; }
      if (k0+2 < H_) { v1.z = Whh1[j*H_+k0+2]; v2.z = Wih2[j*H_+k0+2]; v3.z = Whh2[j*H_+k0+2]; }
      if (k0+3 < H_) { v1.w = Whh1[j*H_+k0+3]; v2.w = Wih2[j*H_+k0+3]; v3.w = Whh2[j*H_+k0+3]; }
    }
    W0[i] = v1; W1[i] = v2; W2[i] = v3;
  }
  for (int i = tid; i < KQ*128; i += NT) WO[i] = WOT[i];
  if (tid < 52) bias2n[tid] = (tid < H_) ? bih2[100 + tid] : 0.f;
  if (tid < BB) samp[tid] = 1;   // SOS
  __syncthreads();

  // loop-invariant decoder biases -> registers
  const float bh1A = bhh1[s + 96];
  const float bh1B = (s < 22) ? bhh1[s + 128] : 0.f;
  const float b2rz0 = bih2[s]      + bhh2[s];
  const float b2rz1 = bih2[s + 32] + bhh2[s + 32];
  const float b2rz2 = bih2[s + 64] + bhh2[s + 64];
  const float b2iA  = bih2[s + 96];
  const float b2hA  = bhh2[s + 96];
  const float b2hB  = (s < 22) ? bhh2[s + 128] : 0.f;

  // =================== DECODER (64 steps) ===================
  for (int t = 0; t < T_; ++t) {
    int c0 = samp[e0], c1 = samp[e1];

    // ---- g1 = giD[c] + gz + h1@Whh1.T  (n rows: bhh1 + gh only) ----
    float acc[5][2];
#pragma unroll
    for (int q = 0; q < 3; ++q) {           // j <= 95 < 100 always
      int j = s + 32*q;
      acc[q][0] = giD[c0*JP + j] + gz[q][0];
      acc[q][1] = giD[c1*JP + j] + gz[q][1];
    }
    if (s < 4) { acc[3][0] = giD[c0*JP + s + 96] + gz[3][0]; acc[3][1] = giD[c1*JP + s + 96] + gz[3][1]; }
    else       { acc[3][0] = bh1A; acc[3][1] = bh1A; }
    acc[4][0] = bh1B; acc[4][1] = bh1B;
#pragma unroll
    for (int kq = 0; kq < KQ; ++kq) {
      float4 ha = hq1[kq*BB + e0];
      float4 hb = hq1[kq*BB + e1];
#pragma unroll
      for (int q = 0; q < 4; ++q) {
        float4 w = W0[kq*JP + s + 32*q];
        acc[q][0] += dot4(w, ha);
        acc[q][1] += dot4(w, hb);
      }
      { float4 w = W0[kq*JP + jq4];
        acc[4][0] += dot4(w, ha);
        acc[4][1] += dot4(w, hb); }
    }
#pragma unroll
    for (int q = 0; q < 4; ++q) {
      int j = s + 32*q;
      gbuf[e0*151 + j] = acc[q][0];
      gbuf[e1*151 + j] = acc[q][1];
    }
    if (s < 22) { int j = s+128; gbuf[e0*151+j] = acc[4][0]; gbuf[e1*151+j] = acc[4][1]; }
    __syncthreads();

    // ---- gate1 -> h1 : u-major -> giD reads coalesced ----
    for (int i = tid; i < BB*64; i += NT) {
      int u = i & 63, e = i >> 6;
      if (u < H_) {
        int c = samp[e];
        float r   = sigf(gbuf[e*151 + u]);
        float zg  = sigf(gbuf[e*151 + 50 + u]);
        float inn = giD[c*JP + 100 + u] + gzn[e*52 + u];
        float n   = tanhf(inn + r*gbuf[e*151 + 100 + u]);
        float* hp = (float*)hq1 + (u>>2)*BB*4 + e*4 + (u&3);
        float ho = *hp;
        *hp = (1.f - zg)*n + zg*ho;
      }
    }
    __syncthreads();

    // ---- g2 split: i-pass (h1new@Wih2.T) then h-pass (h2@Whh2.T) ----
    float a2[5][2], a3A[2];
    a2[0][0] = b2rz0; a2[0][1] = b2rz0;
    a2[1][0] = b2rz1; a2[1][1] = b2rz1;
    a2[2][0] = b2rz2; a2[2][1] = b2rz2;
    a3A[0]   = b2iA;  a3A[1]   = b2iA;
    a2[3][0] = b2hA;  a2[3][1] = b2hA;
    a2[4][0] = b2hB;  a2[4][1] = b2hB;
#pragma unroll
    for (int kq = 0; kq < KQ; ++kq) {       // i-pass
      float4 p1a = hq1[kq*BB + e0], p1b = hq1[kq*BB + e1];
#pragma unroll
      for (int q = 0; q < 3; ++q) {
        float4 wi = W1[kq*JP + s + 32*q];
        a2[q][0] += dot4(wi, p1a);
        a2[q][1] += dot4(wi, p1b);
      }
      { float4 wi = W1[kq*JP + s + 96];
        a3A[0] += dot4(wi, p1a);
        a3A[1] += dot4(wi, p1b); }
    }
#pragma unroll
    for (int kq = 0; kq < KQ; ++kq) {       // h-pass
      float4 p2a = hq2[kq*BB + e0], p2b = hq2[kq*BB + e1];
#pragma unroll
      for (int q = 0; q < 3; ++q) {
        float4 wh = W2[kq*JP + s + 32*q];
        a2[q][0] += dot4(wh, p2a);
        a2[q][1] += dot4(wh, p2b);
      }
      { float4 wh = W2[kq*JP + s + 96];
        a2[3][0] += dot4(wh, p2a);
        a2[3][1] += dot4(wh, p2b); }
      { float4 wh = W2[kq*JP + jq4];
        a2[4][0] += dot4(wh, p2a);
        a2[4][1] += dot4(wh, p2b); }
    }
#pragma unroll
    for (int q = 0; q < 3; ++q) { int j = s + 32*q; gbuf[e0*151+j] = a2[q][0]; gbuf[e1*151+j] = a2[q][1]; }
    { int j = s + 96;
      if (j < 100) { gbuf[e0*151+j] = a3A[0] + a2[3][0]; gbuf[e1*151+j] = a3A[1] + a2[3][1]; }
      else         { gbuf[e0*151+j] = a2[3][0];          gbuf[e1*151+j] = a2[3][1]; } }
    if (s < 22) { int j = s+128; gbuf[e0*151+j] = a2[4][0]; gbuf[e1*151+j] = a2[4][1]; }
    __syncthreads();

    // ---- gate2 -> h2 (e-major: W1 row reads broadcast; no global reads) ----
    for (int i = tid; i < BB*H_; i += NT) {
      int e = i & 31, u = i >> 5;
      float r  = sigf(gbuf[e*151 + u]);
      float zg = sigf(gbuf[e*151 + 50 + u]);
      float inn = bias2n[u];
      for (int kq = 0; kq < KQ; ++kq) {
        float4 w = W1[kq*JP + 100 + u];
        float4 h = hq1[kq*BB + e];
        inn += dot4(w, h);
      }
      float n = tanhf(inn + r*gbuf[e*151 + 100 + u]);
      float* hp = (float*)hq2 + (u>>2)*BB*4 + e*4 + (u&3);
      float ho = *hp;
      *hp = (1.f - zg)*n + zg*ho;
    }
    __syncthreads();

    // ---- o = [h2,z]@Wh2o.T + bh2o ; log_softmax ; argmax ; store ----
    float o[4][2];
#pragma unroll
    for (int q = 0; q < 4; ++q) { o[q][0] = ozr[q][0]; o[q][1] = ozr[q][1]; }
#pragma unroll
    for (int kq = 0; kq < KQ; ++kq) {
      float4 ha = hq2[kq*BB + e0];
      float4 hb = hq2[kq*BB + e1];
#pragma unroll
      for (int q = 0; q < 4; ++q) {
        float4 w = WO[kq*128 + s + 32*q];
        o[q][0] += dot4(w, ha);
        o[q][1] += dot4(w, hb);
      }
    }
#pragma unroll
    for (int ei = 0; ei < 2; ++ei) {
      // argmax (first occurrence) + max via butterfly over the 32-lane half
      float bv = o[0][ei]; int bi = s;
#pragma unroll
      for (int q = 1; q < 4; ++q) {
        int c = s + 32*q;
        if (o[q][ei] > bv) { bv = o[q][ei]; bi = c; }
      }
#pragma unroll
      for (int mask = 16; mask >= 1; mask >>= 1) {
        float ov = __shfl_xor(bv, mask);
        int   oi = __shfl_xor(bi, mask);
        if (ov > bv || (ov == bv && oi < bi)) { bv = ov; bi = oi; }
      }
      float ssum = 0.f;
#pragma unroll
      for (int q = 0; q < 4; ++q) ssum += expf(o[q][ei] - bv);
#pragma unroll
      for (int mask = 16; mask >= 1; mask >>= 1) ssum += __shfl_xor(ssum, mask);
      float lg = logf(ssum);
      int elem = (ei == 0) ? elem0 : elem1;
      long base = (long)elem*T_*C_ + (long)t*C_;
#pragma unroll
      for (int q = 0; q < 4; ++q) out[base + s + 32*q] = o[q][ei] - bv - lg;
      if (s == 0) samp[(ei == 0) ? e0 : e1] = bi;
    }
    __syncthreads();
  }
}

// ---------------------------------------------------------------------------
extern "C" void kernel_launch(void* const* d_in, const int* in_sizes, int n_in,
                              void* d_out, int out_size, void* d_ws, size_t ws_size,
                              hipStream_t stream) {
  const int*   x         = (const int*)  d_in[0];
  const float* embed_enc = (const float*)d_in[1];
  const float* Wih_f     = (const float*)d_in[2];
  const float* Whh_f     = (const float*)d_in[3];
  const float* bih_f     = (const float*)d_in[4];
  const float* bhh_f     = (const float*)d_in[5];
  const float* Wih_b     = (const float*)d_in[6];
  const float* bih_b     = (const float*)d_in[8];
  const float* bhh_b     = (const float*)d_in[9];
  const float* Wh2p      = (const float*)d_in[10];
  const float* bh2p      = (const float*)d_in[11];
  const float* embed_dec = (const float*)d_in[12];
  const float* Wz2h      = (const float*)d_in[13];
  const float* bz2h      = (const float*)d_in[14];
  const float* Wih1      = (const float*)d_in[15];
  const float* Whh1      = (const float*)d_in[16];
  const float* bih1      = (const float*)d_in[17];
  const float* bhh1      = (const float*)d_in[18];
  const float* Wih2      = (const float*)d_in[19];
  const float* Whh2      = (const float*)d_in[20];
  const float* bih2      = (const float*)d_in[21];
  const float* bhh2      = (const float*)d_in[22];
  const float* Wh2o      = (const float*)d_in[23];
  const float* bh2o      = (const float*)d_in[24];
  float* out = (float*)d_out;
  float* ws  = (float*)d_ws;

  hipFuncSetAttribute((const void*)vae_kernel,
                      hipFuncAttributeMaxDynamicSharedMemorySize, SMEM_BYTES);

  tables_kernel<<<128, 256, 0, stream>>>(embed_enc, Wih_f, bih_f, bhh_f,
                                         Wih_b, bih_b, bhh_b,
                                         embed_dec, Wih1, bih1, bhh1, Wh2o, ws);

  vae_kernel<<<B_/BB, NT, SMEM_BYTES, stream>>>(x, Whh_f, bhh_f, Wh2p, bh2p,
                                                Wz2h, bz2h, Wih1, bhh1, Whh1,
                                                Wih2, bih2, bhh2, Whh2,
                                                Wh2o, bh2o, ws, out);
}